// Round 3
// baseline (126.917 us; speedup 1.0000x reference)
//
#include <hip/hip_runtime.h>
#include <math.h>

#define N_NODES 1024
#define N_EVAL 131072
#define NUM_POLES 8
#define PI_D 3.14159265358979323846

// ============================================================================
// V4: register-resident systolic ring.
//
// Evidence from V1-V3: three structurally different kernels (LDS broadcast,
// scalar stream x1, scalar stream x4) all sit at 60-73us, VALUBusy ~21%,
// occupancy counter ~3-5 waves/CU. VALU work is ~12us; every variant leaves
// waves ~95% stalled, and all variants share one trait: the node stream is
// re-fetched through a memory path (LDS or K$) inside the hot loop.
//
// V4 removes the memory system from the hot loop entirely. The full problem
// state (1024 x {node, w, w*v} = 12KB) fits in 48 VGPRs/lane across a wave:
// lane l holds triples [l*16 .. l*16+16). Each lane's point x and its
// (numE,denE,numO,denO) accumulators rotate around the 64-lane ring via
// __shfl (ds_bpermute); after 64 rotations every point has visited all 1024
// nodes and is back home with complete sums. No LDS tile, no s_load, no
// __syncthreads, no cross-lane reduction. Shuffles are placed so each has
// ~32 independent VALU instructions of latency cover:
//   even-half compute -> shfl(aE,bE) covered by odd-half
//   odd-half d's -> shfl(x) covered by odd-half rcp/fma
//   shfl(aO,bO) covered by NEXT step's even-half (aO next needed in odd half)
//
// setup_kernel (unchanged): closed-form barycentric weights, fp64, once.
// For Chebyshev pts of the 2nd kind, 1/prod_{i!=j}(x_j-x_i) =
// (-1)^j*delta_j*2^(n-1)/n; uniform positive scalings cancel in num/den, so
// w_j = (-1)^j * delta_j * prod_m((x_j-pr_m)^2 + pi_m^2).
// Exact node hits poison accumulators -> NaN -> rare per-lane rescan fixup
// (reference semantics: exact-hit column reduces to sum(hit wv)/sum(hit w)).
// ============================================================================

__global__ __launch_bounds__(256) void setup_kernel(
    const float* __restrict__ values,
    const float* __restrict__ poles_real,
    const float* __restrict__ poles_imag,
    float* __restrict__ ws) {
    const int j = blockIdx.x * 256 + threadIdx.x;
    const double nd = cos(PI_D * (double)j / (double)(N_NODES - 1));
    double prod = (j == 0 || j == N_NODES - 1) ? 0.5 : 1.0;
#pragma unroll
    for (int m = 0; m < NUM_POLES; ++m) {
        const double dr = nd - (double)poles_real[m];
        const double di = (double)poles_imag[m];
        prod *= dr * dr + di * di;
    }
    if (j & 1) prod = -prod;
    ws[j]        = (float)nd;
    ws[j + 1024] = (float)prod;
    ws[j + 2048] = (float)(prod * (double)values[j]);
}

__global__ __launch_bounds__(256) void eval_systolic_kernel(
    const float* __restrict__ x_eval,
    const float* __restrict__ ws,
    float* __restrict__ out) {
    const int t = threadIdx.x;
    const int lane = t & 63;
    const int wid  = t >> 6;
    const int pbase = (blockIdx.x * 4 + wid) * 64;

    // ---- prologue: per-lane 16-node register slice (coalesced float4) ----
    float n[16], w[16], v[16];
    {
        const float4* n4 = (const float4*)(ws)        + lane * 4;
        const float4* w4 = (const float4*)(ws + 1024) + lane * 4;
        const float4* v4 = (const float4*)(ws + 2048) + lane * 4;
#pragma unroll
        for (int q = 0; q < 4; ++q) {
            const float4 a = n4[q];
            const float4 b = w4[q];
            const float4 c = v4[q];
            n[q * 4 + 0] = a.x; n[q * 4 + 1] = a.y;
            n[q * 4 + 2] = a.z; n[q * 4 + 3] = a.w;
            w[q * 4 + 0] = b.x; w[q * 4 + 1] = b.y;
            w[q * 4 + 2] = b.z; w[q * 4 + 3] = b.w;
            v[q * 4 + 0] = c.x; v[q * 4 + 1] = c.y;
            v[q * 4 + 2] = c.z; v[q * 4 + 3] = c.w;
        }
    }

    float xr = x_eval[pbase + lane];
    float aE = 0.0f, bE = 0.0f, aO = 0.0f, bO = 0.0f;
    const int src = (lane + 1) & 63;   // pull from next lane; 64 rotations = id

    // ---- 64 systolic steps; hot loop touches registers + 5 shuffles only ----
#pragma unroll 2
    for (int s = 0; s < 64; ++s) {
        // even half: nodes 0..7 for the currently-resident point
#pragma unroll
        for (int k = 0; k < 8; ++k) {
            const float d = xr - n[k];
            const float r = __builtin_amdgcn_rcpf(d);
            aE = fmaf(v[k], r, aE);
            bE = fmaf(w[k], r, bE);
        }
        const float aEn = __shfl(aE, src);
        const float bEn = __shfl(bE, src);

        // odd half: compute all 8 d's first (last use of xr), rotate x early,
        // then the rcp/fma tail covers the x shuffle.
        float d8[8];
#pragma unroll
        for (int k = 0; k < 8; ++k) d8[k] = xr - n[8 + k];
        const float xn = __shfl(xr, src);
#pragma unroll
        for (int k = 0; k < 8; ++k) {
            const float r = __builtin_amdgcn_rcpf(d8[k]);
            aO = fmaf(v[8 + k], r, aO);
            bO = fmaf(w[8 + k], r, bO);
        }
        const float aOn = __shfl(aO, src);
        const float bOn = __shfl(bO, src);

        aE = aEn; bE = bEn; aO = aOn; bO = bOn; xr = xn;
    }

    // ---- epilogue: accumulators are home; divide; rare exact-hit fixup ----
    float res = (aE + aO) / (bE + bO);
    if (__builtin_expect(__builtin_isnan(res), 0)) {
        const float xv = x_eval[pbase + lane];
        float hn = 0.0f, hd = 0.0f;
        for (int jj = 0; jj < N_NODES; ++jj) {
            if (ws[jj] == xv) { hn += ws[2048 + jj]; hd += ws[1024 + jj]; }
        }
        res = hn / hd;
    }
    out[pbase + lane] = res;
}

// ============================================================================
// Fallback (verified round-0 kernel) if the harness workspace is too small.
// ============================================================================
__global__ __launch_bounds__(512, 4) void eval_kernel_fused(
    const float* __restrict__ x_eval,
    const float* __restrict__ values,
    const float* __restrict__ poles_real,
    const float* __restrict__ poles_imag,
    float* __restrict__ out) {
    __shared__ __align__(16) float s_n[N_NODES];
    __shared__ __align__(16) float s_w[N_NODES];
    __shared__ __align__(16) float s_v[N_NODES];
    __shared__ float2 s_r[8][256];

    const int t = threadIdx.x;

#pragma unroll
    for (int h = 0; h < 2; ++h) {
        const int j = t + h * 512;
        const double nd = cos(PI_D * (double)j / (double)(N_NODES - 1));
        double prod = (j == 0 || j == N_NODES - 1) ? 0.5 : 1.0;
#pragma unroll
        for (int m = 0; m < NUM_POLES; ++m) {
            const double dr = nd - (double)poles_real[m];
            const double di = (double)poles_imag[m];
            prod *= dr * dr + di * di;
        }
        if (j & 1) prod = -prod;
        s_n[j] = (float)nd;
        s_w[j] = (float)prod;
        s_v[j] = (float)(prod * (double)values[j]);
    }
    __syncthreads();

    const int lane = t & 63;
    const int wid  = t >> 6;
    const int pbase = blockIdx.x * 256;
    const float x0 = x_eval[pbase + lane];
    const float x1 = x_eval[pbase + 64 + lane];
    const float x2 = x_eval[pbase + 128 + lane];
    const float x3 = x_eval[pbase + 192 + lane];

    const float4* n4 = (const float4*)s_n + wid * 32;
    const float4* w4 = (const float4*)s_w + wid * 32;
    const float4* v4 = (const float4*)s_v + wid * 32;

    float a0 = 0.0f, b0 = 0.0f, a1 = 0.0f, b1 = 0.0f;
    float a2 = 0.0f, b2 = 0.0f, a3 = 0.0f, b3 = 0.0f;

#define NODE(C)                                                            \
    {                                                                      \
        const float d0 = x0 - an.C;                                        \
        const float d1 = x1 - an.C;                                        \
        const float d2 = x2 - an.C;                                        \
        const float d3 = x3 - an.C;                                        \
        const float r0 = __builtin_amdgcn_rcpf(d0);                        \
        const float r1 = __builtin_amdgcn_rcpf(d1);                        \
        const float r2 = __builtin_amdgcn_rcpf(d2);                        \
        const float r3 = __builtin_amdgcn_rcpf(d3);                        \
        a0 = fmaf(av.C, r0, a0); b0 = fmaf(aw.C, r0, b0);                  \
        a1 = fmaf(av.C, r1, a1); b1 = fmaf(aw.C, r1, b1);                  \
        a2 = fmaf(av.C, r2, a2); b2 = fmaf(aw.C, r2, b2);                  \
        a3 = fmaf(av.C, r3, a3); b3 = fmaf(aw.C, r3, b3);                  \
    }

#pragma unroll 4
    for (int q = 0; q < 32; ++q) {
        const float4 an = n4[q];
        const float4 aw = w4[q];
        const float4 av = v4[q];
        NODE(x) NODE(y) NODE(z) NODE(w)
    }
#undef NODE

    s_r[wid][lane]       = make_float2(a0, b0);
    s_r[wid][lane + 64]  = make_float2(a1, b1);
    s_r[wid][lane + 128] = make_float2(a2, b2);
    s_r[wid][lane + 192] = make_float2(a3, b3);
    __syncthreads();

    if (t < 256) {
        float nn = 0.0f, dd = 0.0f;
#pragma unroll
        for (int w = 0; w < 8; ++w) {
            const float2 pr = s_r[w][t];
            nn += pr.x;
            dd += pr.y;
        }
        float res = nn / dd;
        if (__builtin_expect(__builtin_isnan(res), 0)) {
            const float x = x_eval[pbase + t];
            float hn = 0.0f, hd = 0.0f;
            for (int j = 0; j < N_NODES; ++j) {
                if (s_n[j] == x) { hn += s_v[j]; hd += s_w[j]; }
            }
            res = hn / hd;
        }
        out[pbase + t] = res;
    }
}

extern "C" void kernel_launch(void* const* d_in, const int* in_sizes, int n_in,
                              void* d_out, int out_size, void* d_ws, size_t ws_size,
                              hipStream_t stream) {
    const float* x_eval     = (const float*)d_in[0];
    const float* values     = (const float*)d_in[1];
    const float* poles_real = (const float*)d_in[2];
    const float* poles_imag = (const float*)d_in[3];
    float* out = (float*)d_out;

    if (ws_size >= 3 * N_NODES * sizeof(float)) {
        float* ws = (float*)d_ws;
        setup_kernel<<<N_NODES / 256, 256, 0, stream>>>(values, poles_real,
                                                        poles_imag, ws);
        eval_systolic_kernel<<<N_EVAL / 256, 256, 0, stream>>>(x_eval, ws, out);
    } else {
        eval_kernel_fused<<<N_EVAL / 256, 512, 0, stream>>>(
            x_eval, values, poles_real, poles_imag, out);
    }
}